// Round 10
// baseline (226.336 us; speedup 1.0000x reference)
//
#include <hip/hip_runtime.h>
#include <hip/hip_bf16.h>

// out = exp(Q K^T) V, unnormalized. B=4, S=4096, D=64, fp32 in/out.
// Round 10: occupancy to the hardware max. R9 showed per-wave-tile wall
// share (~412 cyc) ~= one wave's serial dependency path, all pipes <40%,
// occupancy ~29% -> waves aren't covering each other's latency. R9's kernel
// is already exactly 64 VGPR = the 8-waves/SIMD cap, so:
//  * single-buffer LDS 18,432 B -> 8 blocks/CU (was 36.8KB/4 blocks)
//  * __launch_bounds__(256, 8); KH=8 kk-splits -> 2048 blocks = 8/CU
//  * grid.x = (kh,b) combo so all 64 q-blocks of one K/V slice land on one
//    XCD (blockIdx%8 heuristic): 4 slices x 256KB = 1MB per XCD L2.
//  * 2 barriers/iter (single buffer) -- overlapped across 8 indep blocks.
//  * reduce8 sums the 8 kh partials (ws traffic +17MB, ~3us -- occupancy
//    win must exceed).

typedef short    s16x4 __attribute__((ext_vector_type(4)));
typedef short    s16x8 __attribute__((ext_vector_type(8)));
typedef _Float16 h16x8 __attribute__((ext_vector_type(8)));
typedef float    fx4   __attribute__((ext_vector_type(4)));
typedef float    fx16  __attribute__((ext_vector_type(16)));

constexpr int S = 4096, D = 64, BQ = 64, BN = 64;
constexpr int KH = 8;                 // kk-range splits
constexpr int NT = S / BN / KH;       // 8 tiles per block
constexpr int KS_SH = 64 * 72;        // shorts per K LDS tile (4608)

__device__ __forceinline__ unsigned short f2bf(float x) {
    unsigned u = __float_as_uint(x);
    u = (u + 0x7FFFu + ((u >> 16) & 1u)) >> 16;   // RNE
    return (unsigned short)u;
}
__device__ __forceinline__ float bf2f(unsigned short h) {
    return __uint_as_float(((unsigned)h) << 16);
}
__device__ __forceinline__ unsigned short f2h(float x) {
    union { _Float16 h; unsigned short s; } u;
    u.h = (_Float16)x;
    return u.s;
}
// bf16x2 pack, round-to-nearest (half-away ties): 3 VALU ops, unbiased.
__device__ __forceinline__ unsigned packbf(float lo, float hi) {
    unsigned a = __float_as_uint(lo) + 0x8000u;
    unsigned b = __float_as_uint(hi) + 0x8000u;
    return __builtin_amdgcn_perm(b, a, 0x07060302u);  // {b[31:16], a[31:16]}
}

__global__ __launch_bounds__(256, 8) void attn_fused3(
    const float* __restrict__ q, const float* __restrict__ k,
    const float* __restrict__ v, float* __restrict__ partial)
{
    __shared__ unsigned short smem[2 * KS_SH];   // 18,432 B: K | Vt (single buf)

    const int tid = threadIdx.x, lane = tid & 63, w = tid >> 6;   // w 0..3
    const int h = lane >> 5, m5 = lane & 31;
    const int mt = w & 1, kkh = w >> 1;      // m-tile (32 rows), kk-half of tile
    // grid: x = combo (kh*4+b) so one K/V slice's 64 q-blocks share an XCD
    const int b = blockIdx.x & 3, kh = blockIdx.x >> 2;
    const int q0 = blockIdx.y * BQ;

    const float* kbase = k + ((size_t)b * S + (size_t)kh * NT * BN) * D;
    const float* vbase = v + ((size_t)b * S + (size_t)kh * NT * BN) * D;

    // ---- Q B-frags fp16 RNE (B[k=h*8+j][n=m5] = Q[q0+mt*32+m5][ks*16+h*8+j]) ----
    h16x8 qf[4];
    {
        const float* qrow = q + ((size_t)b * S + q0 + mt * 32 + m5) * D + h * 8;
        #pragma unroll
        for (int ks = 0; ks < 4; ++ks) {
            float4 a = *(const float4*)(qrow + ks * 16);
            float4 c = *(const float4*)(qrow + ks * 16 + 4);
            qf[ks] = (h16x8){(_Float16)a.x, (_Float16)a.y, (_Float16)a.z, (_Float16)a.w,
                             (_Float16)c.x, (_Float16)c.y, (_Float16)c.z, (_Float16)c.w};
        }
    }

    // ---- staging roles ----
    const int krow0 = tid >> 4;          // K: rows krow0 + i*16
    const int kc4   = (tid & 15) << 2;   //    cols kc4..kc4+3
    const int vd    = tid & 63;          // V: column d (coalesced across lanes)
    const int vg    = w;                 //    rows vg*16 .. +15

    float4 kraw[4];
    float  vraw[16];

    auto load_raw = [&](int t) {
        const float* kt = kbase + (size_t)t * BN * D;
        const float* vt = vbase + (size_t)t * BN * D;
        #pragma unroll
        for (int i = 0; i < 4; ++i)
            kraw[i] = *(const float4*)(kt + (i * 16 + krow0) * D + kc4);
        #pragma unroll
        for (int j = 0; j < 16; ++j)
            vraw[j] = vt[(vg * 16 + j) * D + vd];
    };

    auto cvt_store = [&]() {
        unsigned short* Ksb = smem;
        unsigned short* Vtb = smem + KS_SH;
        #pragma unroll
        for (int i = 0; i < 4; ++i) {            // K: RNE fp16 (bias-safe)
            s16x4 o = {(short)f2h(kraw[i].x), (short)f2h(kraw[i].y),
                       (short)f2h(kraw[i].z), (short)f2h(kraw[i].w)};
            *(s16x4*)&Ksb[(i * 16 + krow0) * 72 + kc4] = o;
        }
        union { unsigned u[4]; s16x8 v; } p0, p1;
        #pragma unroll
        for (int jj = 0; jj < 4; ++jj) {         // V: 3-op nearest bf16 pack
            p0.u[jj] = packbf(vraw[2 * jj],     vraw[2 * jj + 1]);
            p1.u[jj] = packbf(vraw[8 + 2 * jj], vraw[9 + 2 * jj]);
        }
        *(s16x8*)&Vtb[vd * 72 + vg * 16]     = p0.v;
        *(s16x8*)&Vtb[vd * 72 + vg * 16 + 8] = p1.v;
    };

    fx16 oacc[2] = {};   // [dt] O[mt*32.., dt*32..], partial over (kkh, kh)

    auto compute = [&]() {
        const unsigned short* Ksb = smem;
        const unsigned short* Vtb = smem + KS_SH;

        // ---- GEMM1 (fp16 32x32x16): Sc^T[kk 32][m 32], contraction d=64 ----
        fx16 sa = {};
        #pragma unroll
        for (int ks = 0; ks < 4; ++ks) {
            h16x8 a = *(const h16x8*)&Ksb[(kkh * 32 + m5) * 72 + ks * 16 + h * 8];
            sa = __builtin_amdgcn_mfma_f32_32x32x16_f16(a, qf[ks], sa, 0, 0, 0);
        }

        // ---- P = exp(Sc^T), 3-op bf16 pack. C-layout: kk=(r&3)+8*(r>>2)+4h ----
        unsigned p01[8];
        #pragma unroll
        for (int rp = 0; rp < 8; ++rp)
            p01[rp] = packbf(__expf(sa[2 * rp]), __expf(sa[2 * rp + 1]));

        // ---- C-layout -> GEMM2 A-layout: cross-half (lane^32) exchange ----
        union frag { unsigned u[4]; s16x8 v; };
        frag A[2];
#if __has_builtin(__builtin_amdgcn_permlane32_swap)
        typedef unsigned uix2 __attribute__((ext_vector_type(2)));
        uix2 r0 = __builtin_amdgcn_permlane32_swap(p01[0], p01[2], false, false);
        uix2 r1 = __builtin_amdgcn_permlane32_swap(p01[1], p01[3], false, false);
        A[0].u[0] = r0.x; A[0].u[1] = r1.x; A[0].u[2] = r0.y; A[0].u[3] = r1.y;
        uix2 r2 = __builtin_amdgcn_permlane32_swap(p01[4], p01[6], false, false);
        uix2 r3 = __builtin_amdgcn_permlane32_swap(p01[5], p01[7], false, false);
        A[1].u[0] = r2.x; A[1].u[1] = r3.x; A[1].u[2] = r2.y; A[1].u[3] = r3.y;
#else
        unsigned sw[8];
        #pragma unroll
        for (int rp = 0; rp < 8; ++rp)
            sw[rp] = (unsigned)__shfl_xor((int)p01[rp], 32, 64);
        A[0].u[0] = h ? sw[2]  : p01[0];
        A[0].u[1] = h ? sw[3]  : p01[1];
        A[0].u[2] = h ? p01[2] : sw[0];
        A[0].u[3] = h ? p01[3] : sw[1];
        A[1].u[0] = h ? sw[6]  : p01[4];
        A[1].u[1] = h ? sw[7]  : p01[5];
        A[1].u[2] = h ? p01[6] : sw[4];
        A[1].u[3] = h ? p01[7] : sw[5];
#endif

        // ---- GEMM2 (bf16 32x32x16): O += P*V over this wave's 32 kk ----
        #pragma unroll
        for (int ss = 0; ss < 2; ++ss)
            #pragma unroll
            for (int dt = 0; dt < 2; ++dt) {
                s16x8 vv = *(const s16x8*)&Vtb[(dt * 32 + m5) * 72
                                               + kkh * 32 + ss * 16 + h * 8];
                oacc[dt] = __builtin_amdgcn_mfma_f32_32x32x16_bf16(
                    A[ss].v, vv, oacc[dt], 0, 0, 0);
            }
    };

    // ---- pipeline: single buffer, 2 barriers/tile; DMA of t+1 in flight
    //      across compute(t) (registers), staged after the read-barrier ----
    load_raw(0);
    for (int t = 0; t < NT; ++t) {
        cvt_store();                     // waits on kraw/vraw of tile t
        __syncthreads();                 // LDS tile ready
        if (t + 1 < NT) load_raw(t + 1); // in flight across compute
        compute();
        __syncthreads();                 // all waves done reading
    }

    // ---- epilogue: sum the two kkh halves (smem reused), write partial ----
    float* red = (float*)smem;           // 16KB of the 18.4KB buffer
    if (kkh == 1) {
        #pragma unroll
        for (int dt = 0; dt < 2; ++dt)
            #pragma unroll
            for (int r = 0; r < 16; ++r)
                red[((mt * 2 + dt) * 16 + r) * 64 + lane] = oacc[dt][r];
    }
    __syncthreads();
    if (kkh == 0) {
        float* pout = partial + ((size_t)kh * 4 + b) * S * D;   // nbatch==4
        #pragma unroll
        for (int dt = 0; dt < 2; ++dt)
            #pragma unroll
            for (int r = 0; r < 16; ++r) {
                float val = oacc[dt][r] + red[((mt * 2 + dt) * 16 + r) * 64 + lane];
                int row = q0 + mt * 32 + (r & 3) + 8 * (r >> 2) + 4 * h;
                pout[(size_t)row * D + dt * 32 + m5] = val;
            }
    }
}

// ---------------- final reduce: out = sum of 8 kh partials ----------------
__global__ __launch_bounds__(256) void reduce8(
    const float4* __restrict__ p, float4* __restrict__ o, int n4, int stride4)
{
    int i = blockIdx.x * 256 + threadIdx.x;
    if (i < n4) {
        float4 acc = p[i];
        #pragma unroll
        for (int j = 1; j < KH; ++j) {
            float4 x = p[i + (size_t)j * stride4];
            acc.x += x.x; acc.y += x.y; acc.z += x.z; acc.w += x.w;
        }
        o[i] = acc;
    }
}

// ---------------- fallback (known-good round-2 kernel) ----------------
__global__ __launch_bounds__(1024) void attn_fallback(
    const float* __restrict__ q, const float* __restrict__ k,
    const float* __restrict__ v, float* __restrict__ out)
{
    __shared__ unsigned short Kh[64][72];
    __shared__ unsigned short Kl[64][72];
    __shared__ unsigned short Vs[64][68];
    __shared__ unsigned short Pf[64][72];

    const int tid = threadIdx.x, lane = tid & 63, wave = tid >> 6;
    const int quad = lane >> 4, tq = lane & 15;
    const int kkb = wave & 3, mba = wave >> 2;
    const int b = blockIdx.y, q0 = blockIdx.x * 64;
    const float* qb = q + (size_t)b * S * D;
    const float* kb = k + (size_t)b * S * D;
    const float* vb = v + (size_t)b * S * D;
    float* ob = out + (size_t)b * S * D;

    s16x8 qh[2], ql[2];
    {
        const float* qrow = qb + (size_t)(q0 + mba * 16 + tq) * D;
        #pragma unroll
        for (int ks = 0; ks < 2; ++ks) {
            const float* src = qrow + ks * 32 + quad * 8;
            float4 f0 = *(const float4*)src;
            float4 f1 = *(const float4*)(src + 4);
            float f[8] = {f0.x, f0.y, f0.z, f0.w, f1.x, f1.y, f1.z, f1.w};
            #pragma unroll
            for (int j = 0; j < 8; ++j) {
                unsigned short hh = f2bf(f[j]);
                qh[ks][j] = (short)hh;
                ql[ks][j] = (short)f2bf(f[j] - bf2f(hh));
            }
        }
    }
    fx4 oacc = {0.f, 0.f, 0.f, 0.f};
    const int krow = tid >> 4, kc4 = (tid & 15) << 2;
    const int vd = tid & 63, vk = (tid >> 6) << 2;

    for (int t = 0; t < S / 64; ++t) {
        __syncthreads();
        const float* kt = kb + (size_t)(t * 64 + krow) * D;
        const float* vt = vb + (size_t)(t * 64 + vk) * D;
        {
            float4 kv = *(const float4*)(kt + kc4);
            unsigned short h0 = f2bf(kv.x), h1 = f2bf(kv.y), h2 = f2bf(kv.z), h3 = f2bf(kv.w);
            s16x4 a = {(short)h0, (short)h1, (short)h2, (short)h3};
            s16x4 l4 = {(short)f2bf(kv.x - bf2f(h0)), (short)f2bf(kv.y - bf2f(h1)),
                        (short)f2bf(kv.z - bf2f(h2)), (short)f2bf(kv.w - bf2f(h3))};
            *(s16x4*)&Kh[krow][kc4] = a;
            *(s16x4*)&Kl[krow][kc4] = l4;
            const float* vs = vt + vd;
            s16x4 vv = {(short)f2bf(vs[0]), (short)f2bf(vs[D]),
                        (short)f2bf(vs[2 * D]), (short)f2bf(vs[3 * D])};
            *(s16x4*)&Vs[vd][vk] = vv;
        }
        __syncthreads();
        fx4 sacc = {0.f, 0.f, 0.f, 0.f};
        #pragma unroll
        for (int ks = 0; ks < 2; ++ks) {
            s16x8 kah = *(const s16x8*)&Kh[kkb * 16 + tq][ks * 32 + quad * 8];
            s16x8 kal = *(const s16x8*)&Kl[kkb * 16 + tq][ks * 32 + quad * 8];
            sacc = __builtin_amdgcn_mfma_f32_16x16x32_bf16(kah, qh[ks], sacc, 0, 0, 0);
            sacc = __builtin_amdgcn_mfma_f32_16x16x32_bf16(kah, ql[ks], sacc, 0, 0, 0);
            sacc = __builtin_amdgcn_mfma_f32_16x16x32_bf16(kal, qh[ks], sacc, 0, 0, 0);
        }
        s16x4 pp = {(short)f2bf(__expf(sacc[0])), (short)f2bf(__expf(sacc[1])),
                    (short)f2bf(__expf(sacc[2])), (short)f2bf(__expf(sacc[3]))};
        *(s16x4*)&Pf[mba * 16 + tq][kkb * 16 + (quad << 2)] = pp;
        __syncthreads();
        #pragma unroll
        for (int ks = 0; ks < 2; ++ks) {
            s16x8 pa = *(const s16x8*)&Pf[mba * 16 + tq][ks * 32 + quad * 8];
            const unsigned short* vr = &Vs[kkb * 16 + tq][ks * 32 + quad * 8];
            s16x4 va = *(const s16x4*)vr;
            s16x4 vb2 = *(const s16x4*)(vr + 4);
            s16x8 vfull = __builtin_shufflevector(va, vb2, 0, 1, 2, 3, 4, 5, 6, 7);
            oacc = __builtin_amdgcn_mfma_f32_16x16x32_bf16(pa, vfull, oacc, 0, 0, 0);
        }
    }
    #pragma unroll
    for (int r = 0; r < 4; ++r)
        ob[(size_t)(q0 + mba * 16 + quad * 4 + r) * D + kkb * 16 + tq] = oacc[r];
}

extern "C" void kernel_launch(void* const* d_in, const int* in_sizes, int n_in,
                              void* d_out, int out_size, void* d_ws, size_t ws_size,
                              hipStream_t stream) {
    const float* q = (const float*)d_in[0];
    const float* k = (const float*)d_in[1];
    const float* v = (const float*)d_in[2];
    float* out = (float*)d_out;
    const int nbatch = in_sizes[0] / (S * D);   // 4
    const size_t elems = (size_t)nbatch * S * D;

    const size_t need = (size_t)KH * elems * 4;   // 33.6MB of fp32 partials
    if (nbatch == 4 && ws_size >= need && d_ws != nullptr) {
        float* partial = (float*)d_ws;
        dim3 grid(nbatch * KH, S / BQ);    // x = (kh,b) combo -> XCD clustering
        attn_fused3<<<grid, 256, 0, stream>>>(q, k, v, partial);
        const int n4 = (int)(elems / 4);
        reduce8<<<(n4 + 255) / 256, 256, 0, stream>>>(
            (const float4*)partial, (float4*)out, n4, n4);
    } else {
        dim3 grid(S / 64, nbatch);
        attn_fallback<<<grid, 1024, 0, stream>>>(q, k, v, out);
    }
}

// Round 11
// 96.699 us; speedup vs baseline: 2.3406x; 2.3406x over previous
//
#include <hip/hip_runtime.h>
#include <hip/hip_bf16.h>

// out = exp(Q K^T) V, unnormalized. B=4, S=4096, D=64, fp32 in/out.
// Round 11: amortize staging VALU + DMA staging + deep latency cover.
// R9 model: VALU ~515cyc/wave-tile (staging cvt+addressing dominated) vs
// ~680cyc wall share at 2.3 waves/SIMD -> VALU-window-bound. R10 lesson:
// launch_bounds(.,8) caps unified VGPR+AGPR at 64 -> spills (VGPR=32,
// 362MB scratch writes). Fixes here:
//  * prep3: K->fp16 / V->bf16 in EXACT 32x32x16 fragment order, once
//    (conversion+transpose VALU amortized over all 64 q-blocks).
//  * main attn_s3: global_load_lds DMA staging (4 issues/wave/tile; no
//    cvt, no staging registers, no ds_write addressing in loop).
//  * triple-buffer 48KB LDS + s_waitcnt vmcnt(4): tile t+2 DMA stays in
//    flight across 2 full iterations (~1300cyc > 900cyc HBM miss);
//    1 raw barrier/iter; 3 blocks/CU = 12 waves.
//  * kh=4 kk-split (1024 blocks) + reduce4. __expf (absmax margin 4.4x).

typedef short    s16x4 __attribute__((ext_vector_type(4)));
typedef short    s16x8 __attribute__((ext_vector_type(8)));
typedef _Float16 h16x8 __attribute__((ext_vector_type(8)));
typedef float    fx4   __attribute__((ext_vector_type(4)));
typedef float    fx16  __attribute__((ext_vector_type(16)));

constexpr int S = 4096, D = 64, BQ = 64, BN = 64;
constexpr int KH = 4;                  // kk-range splits
constexpr int NT = S / BN / KH;        // 16 tiles per block
constexpr int NTILES = S / BN;         // 64 tiles per batch
constexpr int TILE_SH  = 8 * 512;      // 4096 shorts (8KB) per array per tile
constexpr int BATCH_SH = NTILES * TILE_SH;   // 262144 shorts per batch

__device__ __forceinline__ unsigned short f2bf(float x) {
    unsigned u = __float_as_uint(x);
    u = (u + 0x7FFFu + ((u >> 16) & 1u)) >> 16;   // RNE
    return (unsigned short)u;
}
__device__ __forceinline__ float bf2f(unsigned short h) {
    return __uint_as_float(((unsigned)h) << 16);
}
__device__ __forceinline__ unsigned short f2h(float x) {
    union { _Float16 h; unsigned short s; } u;
    u.h = (_Float16)x;
    return u.s;
}
// bf16x2 pack, round-to-nearest (half-away ties): 3 VALU ops, unbiased.
__device__ __forceinline__ unsigned packbf(float lo, float hi) {
    unsigned a = __float_as_uint(lo) + 0x8000u;
    unsigned b = __float_as_uint(hi) + 0x8000u;
    return __builtin_amdgcn_perm(b, a, 0x07060302u);  // {b[31:16], a[31:16]}
}

// -------- prep3: per-64-row tile, K -> fp16 A-frag order, V -> bf16 B-frag --
// K chunk c = kkh*4+ks      : [l][j] = K[t*64 + kkh*32 + (l&31)][ks*16 + (l>>5)*8 + j]
// V chunk c = kkh*4+ss*2+dt : [l][j] = V[t*64 + kkh*32 + ss*16 + (l>>5)*8 + j][dt*32 + (l&31)]
__global__ __launch_bounds__(256) void prep3(
    const float* __restrict__ k, const float* __restrict__ v,
    unsigned short* __restrict__ kf, unsigned short* __restrict__ vf)
{
    __shared__ unsigned short tile[64 * 72];    // stride 72 (pad)
    const int tid   = threadIdx.x;
    const int which = blockIdx.x & 1;           // 0 = K, 1 = V
    const int t     = (blockIdx.x >> 1) & 63;
    const int b     = blockIdx.x >> 7;
    const float* src = (which ? v : k) + ((size_t)b * S + t * BN) * D;

    #pragma unroll
    for (int i = 0; i < 4; ++i) {               // 64x64 fp32, coalesced float4
        int f   = i * 256 + tid;
        int row = f >> 4;
        int c4  = (f & 15) << 2;
        float4 x = *(const float4*)(src + row * D + c4);
        s16x4 o;
        if (which) o = (s16x4){(short)f2bf(x.x), (short)f2bf(x.y),
                               (short)f2bf(x.z), (short)f2bf(x.w)};
        else       o = (s16x4){(short)f2h(x.x), (short)f2h(x.y),
                               (short)f2h(x.z), (short)f2h(x.w)};
        *(s16x4*)&tile[row * 72 + c4] = o;
    }
    __syncthreads();

    const int l = tid & 63;
    unsigned short* dst = (which ? vf : kf) + (size_t)b * BATCH_SH + t * TILE_SH;
    #pragma unroll
    for (int i = 0; i < 2; ++i) {
        int c = (tid >> 6) * 2 + i;             // chunk 0..7
        s16x8 o;
        if (which == 0) {
            int row = (c >> 2) * 32 + (l & 31);
            int col = (c & 3) * 16 + (l >> 5) * 8;
            o = *(const s16x8*)&tile[row * 72 + col];       // b128, aligned
        } else {
            int r0  = (c >> 2) * 32 + ((c >> 1) & 1) * 16 + (l >> 5) * 8;
            int col = (c & 1) * 32 + (l & 31);
            #pragma unroll
            for (int j = 0; j < 8; ++j) o[j] = (short)tile[(r0 + j) * 72 + col];
        }
        *(s16x8*)(dst + c * 512 + l * 8) = o;               // coalesced b128
    }
}

// ---------------- main: DMA-staged, triple-buffered, vmcnt(4) ----------------
__global__ __launch_bounds__(256, 4) void attn_s3(
    const float* __restrict__ q, const unsigned short* __restrict__ kf,
    const unsigned short* __restrict__ vf, float* __restrict__ partial)
{
    __shared__ unsigned short smem[3 * 2 * TILE_SH];   // 49152 B: 3 x (K 8K | V 8K)

    const int tid = threadIdx.x, lane = tid & 63, w = tid >> 6;   // w 0..3
    const int h = lane >> 5, m5 = lane & 31;
    const int mt = w & 1, kkh = w >> 1;      // m-tile (32 rows), kk-half of tile
    const int b = blockIdx.y, q0 = blockIdx.x * BQ, kh = blockIdx.z;

    const unsigned short* kfb = kf + (size_t)b * BATCH_SH + (size_t)kh * NT * TILE_SH;
    const unsigned short* vfb = vf + (size_t)b * BATCH_SH + (size_t)kh * NT * TILE_SH;

    // ---- Q B-frags fp16 RNE (B[k=h*8+j][n=m5] = Q[q0+mt*32+m5][ks*16+h*8+j]) ----
    h16x8 qf[4];
    {
        const float* qrow = q + ((size_t)b * S + q0 + mt * 32 + m5) * D + h * 8;
        #pragma unroll
        for (int ks = 0; ks < 4; ++ks) {
            float4 a = *(const float4*)(qrow + ks * 16);
            float4 c = *(const float4*)(qrow + ks * 16 + 4);
            qf[ks] = (h16x8){(_Float16)a.x, (_Float16)a.y, (_Float16)a.z, (_Float16)a.w,
                             (_Float16)c.x, (_Float16)c.y, (_Float16)c.z, (_Float16)c.w};
        }
    }

    fx16 oacc[2] = {};   // [dt] O[mt*32.., dt*32..], partial over (kkh, kh)

    // Wave w DMAs chunks {2w, 2w+1} of K and of V: 4 x 1KB per tile.
    auto issue = [&](int t, int bi) {
        unsigned short* base = &smem[bi * 2 * TILE_SH];
        const size_t goff = (size_t)t * TILE_SH;
        #pragma unroll
        for (int i = 0; i < 2; ++i) {
            const int c = w * 2 + i;
            __builtin_amdgcn_global_load_lds(
                (const __attribute__((address_space(1))) unsigned int*)
                    (kfb + goff + c * 512 + lane * 8),
                (__attribute__((address_space(3))) unsigned int*)
                    (base + c * 512 + lane * 8), 16, 0, 0);
            __builtin_amdgcn_global_load_lds(
                (const __attribute__((address_space(1))) unsigned int*)
                    (vfb + goff + c * 512 + lane * 8),
                (__attribute__((address_space(3))) unsigned int*)
                    (base + TILE_SH + c * 512 + lane * 8), 16, 0, 0);
        }
    };

    issue(0, 0);
    issue(1, 1);

    for (int t = 0; t < NT; ++t) {
        const int bi = t % 3;
        // Drain tile t's 4 DMAs (oldest); leave tile t+1's 4 in flight.
        __asm__ volatile("" ::: "memory");
        __builtin_amdgcn_s_waitcnt(0x0F74);   // vmcnt(4)
        __builtin_amdgcn_s_barrier();
        __asm__ volatile("" ::: "memory");
        issue((t + 2) & (NT - 1), (t + 2) % 3);   // 2-iteration cover

        const unsigned short* Kb = &smem[bi * 2 * TILE_SH];
        const unsigned short* Vb = Kb + TILE_SH;

        // ---- GEMM1 (fp16 32x32x16): Sc^T[kk 32][m 32], contraction d=64 ----
        fx16 sa = {};
        #pragma unroll
        for (int ks = 0; ks < 4; ++ks) {
            h16x8 a = *(const h16x8*)(Kb + (kkh * 4 + ks) * 512 + lane * 8);
            sa = __builtin_amdgcn_mfma_f32_32x32x16_f16(a, qf[ks], sa, 0, 0, 0);
        }

        // ---- P = exp(Sc^T), 3-op bf16 pack. C-layout: kk=(r&3)+8*(r>>2)+4h ----
        unsigned p01[8];
        #pragma unroll
        for (int rp = 0; rp < 8; ++rp)
            p01[rp] = packbf(__expf(sa[2 * rp]), __expf(sa[2 * rp + 1]));

        // ---- C-layout -> GEMM2 A-layout: cross-half (lane^32) exchange ----
        union frag { unsigned u[4]; s16x8 v; };
        frag A[2];
#if __has_builtin(__builtin_amdgcn_permlane32_swap)
        typedef unsigned uix2 __attribute__((ext_vector_type(2)));
        uix2 r0 = __builtin_amdgcn_permlane32_swap(p01[0], p01[2], false, false);
        uix2 r1 = __builtin_amdgcn_permlane32_swap(p01[1], p01[3], false, false);
        A[0].u[0] = r0.x; A[0].u[1] = r1.x; A[0].u[2] = r0.y; A[0].u[3] = r1.y;
        uix2 r2 = __builtin_amdgcn_permlane32_swap(p01[4], p01[6], false, false);
        uix2 r3 = __builtin_amdgcn_permlane32_swap(p01[5], p01[7], false, false);
        A[1].u[0] = r2.x; A[1].u[1] = r3.x; A[1].u[2] = r2.y; A[1].u[3] = r3.y;
#else
        unsigned sw[8];
        #pragma unroll
        for (int rp = 0; rp < 8; ++rp)
            sw[rp] = (unsigned)__shfl_xor((int)p01[rp], 32, 64);
        A[0].u[0] = h ? sw[2]  : p01[0];
        A[0].u[1] = h ? sw[3]  : p01[1];
        A[0].u[2] = h ? p01[2] : sw[0];
        A[0].u[3] = h ? p01[3] : sw[1];
        A[1].u[0] = h ? sw[6]  : p01[4];
        A[1].u[1] = h ? sw[7]  : p01[5];
        A[1].u[2] = h ? p01[6] : sw[4];
        A[1].u[3] = h ? p01[7] : sw[5];
#endif

        // ---- GEMM2 (bf16 32x32x16): O += P*V over this wave's 32 kk ----
        #pragma unroll
        for (int ss = 0; ss < 2; ++ss)
            #pragma unroll
            for (int dt = 0; dt < 2; ++dt) {
                s16x8 vv = *(const s16x8*)(Vb + (kkh * 4 + ss * 2 + dt) * 512
                                           + lane * 8);
                oacc[dt] = __builtin_amdgcn_mfma_f32_32x32x16_bf16(
                    A[ss].v, vv, oacc[dt], 0, 0, 0);
            }
    }

    // ---- epilogue: sum the two kkh halves (smem reused), write partial ----
    __syncthreads();                     // full drain incl. leftover DMA
    float* red = (float*)smem;           // 16KB of the 48KB buffer
    if (kkh == 1) {
        #pragma unroll
        for (int dt = 0; dt < 2; ++dt)
            #pragma unroll
            for (int r = 0; r < 16; ++r)
                red[((mt * 2 + dt) * 16 + r) * 64 + lane] = oacc[dt][r];
    }
    __syncthreads();
    if (kkh == 0) {
        float* pout = partial + ((size_t)kh * 4 + b) * S * D;   // nbatch==4
        #pragma unroll
        for (int dt = 0; dt < 2; ++dt)
            #pragma unroll
            for (int r = 0; r < 16; ++r) {
                float val = oacc[dt][r] + red[((mt * 2 + dt) * 16 + r) * 64 + lane];
                int row = q0 + mt * 32 + (r & 3) + 8 * (r >> 2) + 4 * h;
                pout[(size_t)row * D + dt * 32 + m5] = val;
            }
    }
}

// ---------------- final reduce: out = sum of 4 kh partials ----------------
__global__ __launch_bounds__(256) void reduce4(
    const float4* __restrict__ p, float4* __restrict__ o, int n4, int stride4)
{
    int i = blockIdx.x * 256 + threadIdx.x;
    if (i < n4) {
        float4 a = p[i], b = p[i + stride4],
               c = p[i + 2 * stride4], d = p[i + 3 * stride4];
        o[i] = make_float4(a.x + b.x + c.x + d.x, a.y + b.y + c.y + d.y,
                           a.z + b.z + c.z + d.z, a.w + b.w + c.w + d.w);
    }
}

// ---------------- fallback (known-good round-2 kernel) ----------------
__global__ __launch_bounds__(1024) void attn_fallback(
    const float* __restrict__ q, const float* __restrict__ k,
    const float* __restrict__ v, float* __restrict__ out)
{
    __shared__ unsigned short Kh[64][72];
    __shared__ unsigned short Kl[64][72];
    __shared__ unsigned short Vs[64][68];
    __shared__ unsigned short Pf[64][72];

    const int tid = threadIdx.x, lane = tid & 63, wave = tid >> 6;
    const int quad = lane >> 4, tq = lane & 15;
    const int kkb = wave & 3, mba = wave >> 2;
    const int b = blockIdx.y, q0 = blockIdx.x * 64;
    const float* qb = q + (size_t)b * S * D;
    const float* kb = k + (size_t)b * S * D;
    const float* vb = v + (size_t)b * S * D;
    float* ob = out + (size_t)b * S * D;

    s16x8 qh[2], ql[2];
    {
        const float* qrow = qb + (size_t)(q0 + mba * 16 + tq) * D;
        #pragma unroll
        for (int ks = 0; ks < 2; ++ks) {
            const float* src = qrow + ks * 32 + quad * 8;
            float4 f0 = *(const float4*)src;
            float4 f1 = *(const float4*)(src + 4);
            float f[8] = {f0.x, f0.y, f0.z, f0.w, f1.x, f1.y, f1.z, f1.w};
            #pragma unroll
            for (int j = 0; j < 8; ++j) {
                unsigned short hh = f2bf(f[j]);
                qh[ks][j] = (short)hh;
                ql[ks][j] = (short)f2bf(f[j] - bf2f(hh));
            }
        }
    }
    fx4 oacc = {0.f, 0.f, 0.f, 0.f};
    const int krow = tid >> 4, kc4 = (tid & 15) << 2;
    const int vd = tid & 63, vk = (tid >> 6) << 2;

    for (int t = 0; t < S / 64; ++t) {
        __syncthreads();
        const float* kt = kb + (size_t)(t * 64 + krow) * D;
        const float* vt = vb + (size_t)(t * 64 + vk) * D;
        {
            float4 kv = *(const float4*)(kt + kc4);
            unsigned short h0 = f2bf(kv.x), h1 = f2bf(kv.y), h2 = f2bf(kv.z), h3 = f2bf(kv.w);
            s16x4 a = {(short)h0, (short)h1, (short)h2, (short)h3};
            s16x4 l4 = {(short)f2bf(kv.x - bf2f(h0)), (short)f2bf(kv.y - bf2f(h1)),
                        (short)f2bf(kv.z - bf2f(h2)), (short)f2bf(kv.w - bf2f(h3))};
            *(s16x4*)&Kh[krow][kc4] = a;
            *(s16x4*)&Kl[krow][kc4] = l4;
            const float* vs = vt + vd;
            s16x4 vv = {(short)f2bf(vs[0]), (short)f2bf(vs[D]),
                        (short)f2bf(vs[2 * D]), (short)f2bf(vs[3 * D])};
            *(s16x4*)&Vs[vd][vk] = vv;
        }
        __syncthreads();
        fx4 sacc = {0.f, 0.f, 0.f, 0.f};
        #pragma unroll
        for (int ks = 0; ks < 2; ++ks) {
            s16x8 kah = *(const s16x8*)&Kh[kkb * 16 + tq][ks * 32 + quad * 8];
            s16x8 kal = *(const s16x8*)&Kl[kkb * 16 + tq][ks * 32 + quad * 8];
            sacc = __builtin_amdgcn_mfma_f32_16x16x32_bf16(kah, qh[ks], sacc, 0, 0, 0);
            sacc = __builtin_amdgcn_mfma_f32_16x16x32_bf16(kah, ql[ks], sacc, 0, 0, 0);
            sacc = __builtin_amdgcn_mfma_f32_16x16x32_bf16(kal, qh[ks], sacc, 0, 0, 0);
        }
        s16x4 pp = {(short)f2bf(__expf(sacc[0])), (short)f2bf(__expf(sacc[1])),
                    (short)f2bf(__expf(sacc[2])), (short)f2bf(__expf(sacc[3]))};
        *(s16x4*)&Pf[mba * 16 + tq][kkb * 16 + (quad << 2)] = pp;
        __syncthreads();
        #pragma unroll
        for (int ks = 0; ks < 2; ++ks) {
            s16x8 pa = *(const s16x8*)&Pf[mba * 16 + tq][ks * 32 + quad * 8];
            const unsigned short* vr = &Vs[kkb * 16 + tq][ks * 32 + quad * 8];
            s16x4 va = *(const s16x4*)vr;
            s16x4 vb2 = *(const s16x4*)(vr + 4);
            s16x8 vfull = __builtin_shufflevector(va, vb2, 0, 1, 2, 3, 4, 5, 6, 7);
            oacc = __builtin_amdgcn_mfma_f32_16x16x32_bf16(pa, vfull, oacc, 0, 0, 0);
        }
    }
    #pragma unroll
    for (int r = 0; r < 4; ++r)
        ob[(size_t)(q0 + mba * 16 + quad * 4 + r) * D + kkb * 16 + tq] = oacc[r];
}

extern "C" void kernel_launch(void* const* d_in, const int* in_sizes, int n_in,
                              void* d_out, int out_size, void* d_ws, size_t ws_size,
                              hipStream_t stream) {
    const float* q = (const float*)d_in[0];
    const float* k = (const float*)d_in[1];
    const float* v = (const float*)d_in[2];
    float* out = (float*)d_out;
    const int nbatch = in_sizes[0] / (S * D);   // 4
    const size_t elems = (size_t)nbatch * S * D;

    // ws: kf fp16 2MB | vf bf16 2MB | partial[KH] fp32 16.8MB
    const size_t need = elems * 2 * 2 + (size_t)KH * elems * 4;
    if (nbatch == 4 && ws_size >= need && d_ws != nullptr) {
        unsigned short* kf = (unsigned short*)d_ws;
        unsigned short* vf = kf + elems;
        float* partial = (float*)(vf + elems);

        prep3<<<2 * nbatch * NTILES, 256, 0, stream>>>(k, v, kf, vf);
        dim3 grid(S / BQ, nbatch, KH);
        attn_s3<<<grid, 256, 0, stream>>>(q, kf, vf, partial);
        const int n4 = (int)(elems / 4);
        reduce4<<<(n4 + 255) / 256, 256, 0, stream>>>(
            (const float4*)partial, (float4*)out, n4, n4);
    } else {
        dim3 grid(S / 64, nbatch);
        attn_fallback<<<grid, 1024, 0, stream>>>(q, k, v, out);
    }
}